// Round 10
// baseline (491.700 us; speedup 1.0000x reference)
//
#include <hip/hip_runtime.h>

// B=8, C=128, H=W=256, P=2, R=2, WP=3, HID=8. Output xp: (B,C,260,260) fp32.
// Single kernel, 1024 blocks (one per (b,c) slice) x 512 threads:
//  1) zero-init LDS line buffers; barrier (t~0, cheap).
//  2) issue border input loads into REGISTERS (5 rows coalesced + 5 cols
//     strided, ~6 loads/thread), fire-and-forget — latency hides under (3).
//  3) STREAM the interior immediately: 65 aligned float4 per row
//     (probe_wpat pattern, >=5.8 TB/s), frame cols get junk.
//  4) threadfence + barrier; dump regs -> LDS; barrier.
//  5) 8-stage border program in LDS (SGPR weights, pure VALU+LDS).
//  6) patch frame: rows 0,1,258,259 full width + col strips 0,1/258,259
//     (overwrites step-3 junk; ordering guaranteed by the fence).

typedef float f32x4 __attribute__((ext_vector_type(4)));
typedef float f32x2 __attribute__((ext_vector_type(2)));

__device__ __forceinline__ int bmap(int r) { return r < 4 ? r : r - 251; }

template <int S>
__device__ __forceinline__ float mlp6(const float* v,
                                      const float* __restrict__ w1, const float* __restrict__ b1,
                                      const float* __restrict__ w2, const float* __restrict__ b2,
                                      const float* __restrict__ w3, const float* __restrict__ b3)
{
    const float* __restrict__ W1 = w1 + S * 48;  // [8][6]
    const float* __restrict__ B1 = b1 + S * 8;
    const float* __restrict__ W2 = w2 + S * 64;  // [8][8]
    const float* __restrict__ B2 = b2 + S * 8;
    const float* __restrict__ W3 = w3 + S * 8;
    const float  b3s = b3[S];

    float h1[8];
#pragma unroll
    for (int h = 0; h < 8; ++h) {
        float a = B1[h];
#pragma unroll
        for (int q = 0; q < 6; ++q) a = fmaf(v[q], W1[h * 6 + q], a);
        h1[h] = fmaxf(a, 0.f);
    }
    float h2[8];
#pragma unroll
    for (int g = 0; g < 8; ++g) {
        float a = B2[g];
#pragma unroll
        for (int h = 0; h < 8; ++h) a = fmaf(h1[h], W2[g * 8 + h], a);
        h2[g] = fmaxf(a, 0.f);
    }
    float o = b3s;
#pragma unroll
    for (int g = 0; g < 8; ++g) o = fmaf(h2[g], W3[g], o);
    return fmaxf(o, 0.f);
}

template <int S>
__device__ __forceinline__ void hstage(int it, int tid,
                                       float (*rowS)[260], float (*colS)[260],
                                       const float* __restrict__ w1, const float* __restrict__ b1,
                                       const float* __restrict__ w2, const float* __restrict__ b2,
                                       const float* __restrict__ w3, const float* __restrict__ b3)
{
    int rin0, rin1, rout;
    if (S == 0) { rin0 = 2 - it;   rin1 = 3 - it;   rout = 1 - it;   }
    else        { rin0 = 255 + it; rin1 = 256 + it; rout = 258 + it; }
    const int a0 = bmap(rin0), a1 = bmap(rin1), ao = bmap(rout);
    for (int j0 = tid; j0 < 258; j0 += 512) {
        int j = j0 + 1;
        float v[6];
        v[0] = rowS[a0][j - 1]; v[1] = rowS[a0][j]; v[2] = rowS[a0][j + 1];
        v[3] = rowS[a1][j - 1]; v[4] = rowS[a1][j]; v[5] = rowS[a1][j + 1];
        float o = mlp6<S>(v, w1, b1, w2, b2, w3, b3);
        rowS[ao][j] = o;
        if (j < 4 || j >= 255) colS[bmap(j)][rout] = o;  // keep col views consistent
    }
}

template <int S>
__device__ __forceinline__ void vstage(int it, int tid,
                                       float (*rowS)[260], float (*colS)[260],
                                       const float* __restrict__ w1, const float* __restrict__ b1,
                                       const float* __restrict__ w2, const float* __restrict__ b2,
                                       const float* __restrict__ w3, const float* __restrict__ b3)
{
    int cin0, cin1, cout;
    if (S == 2) { cin0 = 2 - it;   cin1 = 3 - it;   cout = 1 - it;   }
    else        { cin0 = 255 + it; cin1 = 256 + it; cout = 258 + it; }
    const int a0 = bmap(cin0), a1 = bmap(cin1), ao = bmap(cout);
    for (int r0 = tid; r0 < 258; r0 += 512) {
        int r = r0 + 1;
        float v[6];
        v[0] = colS[a0][r - 1]; v[1] = colS[a0][r]; v[2] = colS[a0][r + 1];
        v[3] = colS[a1][r - 1]; v[4] = colS[a1][r]; v[5] = colS[a1][r + 1];
        float o = mlp6<S>(v, w1, b1, w2, b2, w3, b3);
        colS[ao][r] = o;
        if (r < 4 || r >= 255) rowS[bmap(r)][cout] = o;  // keep row views consistent
    }
}

__global__ __launch_bounds__(512) void padding_kernel(
    const float* __restrict__ x,
    const float* __restrict__ w1, const float* __restrict__ b1,
    const float* __restrict__ w2, const float* __restrict__ b2,
    const float* __restrict__ w3, const float* __restrict__ b3,
    float* __restrict__ out)
{
    const int tid = threadIdx.x;
    const int bc  = blockIdx.x;                     // b*128 + c
    const float* xs = x + (size_t)bc * 65536;
    float*       os = out + (size_t)bc * 67600;

    // tracked xp rows/cols {0,1,2,3,255,256,257,258,259} -> 0..8
    __shared__ float rowS[9][260];
    __shared__ float colS[9][260];

    // 1) zero-init + early barrier (settles zero-vs-data write order)
    for (int idx = tid; idx < 9 * 260; idx += 512) {
        (&rowS[0][0])[idx] = 0.f;
        (&colS[0][0])[idx] = 0.f;
    }
    __syncthreads();

    // 2) issue border-input loads into registers, fire-and-forget.
    //    item idx in [0,1280): which=idx/256 -> x row/col {0,1,253,254,255}
    const int t0 = tid & 255;
    const int wh0 = tid >> 8;                       // 0..1 (items tid)
    const int wh1 = wh0 + 2;                        // 2..3 (items tid+512)
    const int xr0 = wh0;                            // 0 or 1
    const int xr1 = 251 + wh1;                      // 253 or 254
    float rowR0 = xs[xr0 * 256 + t0];
    float rowR1 = xs[xr1 * 256 + t0];
    float colR0 = xs[t0 * 256 + xr0];
    float colR1 = xs[t0 * 256 + xr1];
    float rowR2 = 0.f, colR2 = 0.f;
    if (tid < 256) {                                // items tid+1024: which=4
        rowR2 = xs[255 * 256 + t0];
        colR2 = xs[t0 * 256 + 255];
    }

    // 3) interior stream: 65 aligned float4 per row, junk at frame cols
    for (int idx = tid; idx < 256 * 65; idx += 512) {
        int r = idx / 65;
        int k = idx - r * 65;
        float*       orow = os + (size_t)(r + 2) * 260;
        const float* xrow = xs + (size_t)r * 256;
        f32x4 val;
        if (k == 0) {            // xp cols 0..3: {junk,junk,x0,x1}
            f32x2 a = *(const f32x2*)(xrow);
            val = (f32x4){a.x, a.y, a.x, a.y};
        } else if (k == 64) {    // xp cols 256..259: {x254,x255,junk,junk}
            f32x2 c = *(const f32x2*)(xrow + 254);
            val = (f32x4){c.x, c.y, c.x, c.y};
        } else {                 // xp cols 4k..4k+3 = x[4k-2..4k+1]
            f32x2 a = *(const f32x2*)(xrow + 4 * k - 2);
            f32x2 c = *(const f32x2*)(xrow + 4 * k);
            val = (f32x4){a.x, a.y, c.x, c.y};
        }
        *(f32x4*)(orow + 4 * k) = val;
    }

    // 4) order junk-writes before patch writes; dump regs -> LDS
    __threadfence();
    rowS[2 + wh0][2 + t0] = rowR0;
    rowS[2 + wh1][2 + t0] = rowR1;
    colS[2 + wh0][2 + t0] = colR0;
    colS[2 + wh1][2 + t0] = colR1;
    if (tid < 256) {
        rowS[6][2 + t0] = rowR2;
        colS[6][2 + t0] = colR2;
    }
    __syncthreads();

    // 5) border program — pure LDS+VALU
    for (int it = 0; it < 2; ++it) {
        hstage<0>(it, tid, rowS, colS, w1, b1, w2, b2, w3, b3);
        hstage<1>(it, tid, rowS, colS, w1, b1, w2, b2, w3, b3);
        __syncthreads();
        vstage<2>(it, tid, rowS, colS, w1, b1, w2, b2, w3, b3);
        vstage<3>(it, tid, rowS, colS, w1, b1, w2, b2, w3, b3);
        __syncthreads();
    }

    // 6) patch frame. rows 0,1,258,259 full width (corners = 0 as in ref)
    for (int idx = tid; idx < 4 * 260; idx += 512) {
        int w = idx / 260, cc = idx % 260;
        int rr = w < 2 ? w : 256 + w;               // 0,1,258,259
        os[(size_t)rr * 260 + cc] = rowS[bmap(rr)][cc];
    }
    // col strips: cols 0,1 and 258,259 for rows 2..257 (overwrite stream junk)
    for (int idx = tid; idx < 2 * 256; idx += 512) {
        int w = idx >> 8;                           // 0 = left, 1 = right
        int r = (idx & 255) + 2;
        float* orow = os + (size_t)r * 260;
        if (w == 0) *(f32x2*)(orow)       = (f32x2){colS[0][r], colS[1][r]};
        else        *(f32x2*)(orow + 258) = (f32x2){colS[7][r], colS[8][r]};
    }
}

extern "C" void kernel_launch(void* const* d_in, const int* in_sizes, int n_in,
                              void* d_out, int out_size, void* d_ws, size_t ws_size,
                              hipStream_t stream)
{
    const float* x  = (const float*)d_in[0];
    const float* w1 = (const float*)d_in[1];
    const float* b1 = (const float*)d_in[2];
    const float* w2 = (const float*)d_in[3];
    const float* b2 = (const float*)d_in[4];
    const float* w3 = (const float*)d_in[5];
    const float* b3 = (const float*)d_in[6];
    float* out = (float*)d_out;

    padding_kernel<<<1024, 512, 0, stream>>>(x, w1, b1, w2, b2, w3, b3, out);
}

// Round 11
// 173.157 us; speedup vs baseline: 2.8396x; 2.8396x over previous
//
#include <hip/hip_runtime.h>

// B=8, C=128, H=W=256, P=2, R=2, WP=3, HID=8. Output xp: (B,C,260,260) fp32.
// Single kernel, 1024 blocks (one per (b,c) slice) x 512 threads.
// ORDER: stream first, border after (R3 reversed):
//  1) zero LDS line buffers (overlaps stream issue).
//  2) STREAM interior rows xp[2..257] as 65 aligned float4 each
//     (probe-proven pattern, >=5.6 TB/s); frame cols get junk.
//  3) __syncthreads() — implicit vmcnt(0) drain orders junk writes before
//     the later patch writes (same block -> same CU -> same XCD L2).
//  4) gather border inputs: 5 x-rows coalesced + 5 x-cols strided — now
//     STAGGERED across blocks and against a WARM L2/L3 (x just streamed).
//  5) 4-stage border program in LDS (SGPR weights), pure LDS+VALU.
//  6) patch frame: rows 0,1,258,259 full width + col strips 0,1/258,259.

typedef float f32x4 __attribute__((ext_vector_type(4)));
typedef float f32x2 __attribute__((ext_vector_type(2)));

__device__ __forceinline__ int bmap(int r) { return r < 4 ? r : r - 251; }

template <int S>
__device__ __forceinline__ float mlp6(const float* v,
                                      const float* __restrict__ w1, const float* __restrict__ b1,
                                      const float* __restrict__ w2, const float* __restrict__ b2,
                                      const float* __restrict__ w3, const float* __restrict__ b3)
{
    const float* __restrict__ W1 = w1 + S * 48;  // [8][6]
    const float* __restrict__ B1 = b1 + S * 8;
    const float* __restrict__ W2 = w2 + S * 64;  // [8][8]
    const float* __restrict__ B2 = b2 + S * 8;
    const float* __restrict__ W3 = w3 + S * 8;
    const float  b3s = b3[S];

    float h1[8];
#pragma unroll
    for (int h = 0; h < 8; ++h) {
        float a = B1[h];
#pragma unroll
        for (int q = 0; q < 6; ++q) a = fmaf(v[q], W1[h * 6 + q], a);
        h1[h] = fmaxf(a, 0.f);
    }
    float h2[8];
#pragma unroll
    for (int g = 0; g < 8; ++g) {
        float a = B2[g];
#pragma unroll
        for (int h = 0; h < 8; ++h) a = fmaf(h1[h], W2[g * 8 + h], a);
        h2[g] = fmaxf(a, 0.f);
    }
    float o = b3s;
#pragma unroll
    for (int g = 0; g < 8; ++g) o = fmaf(h2[g], W3[g], o);
    return fmaxf(o, 0.f);
}

template <int S>
__device__ __forceinline__ void hstage(int it, int tid,
                                       float (*rowS)[260], float (*colS)[260],
                                       const float* __restrict__ w1, const float* __restrict__ b1,
                                       const float* __restrict__ w2, const float* __restrict__ b2,
                                       const float* __restrict__ w3, const float* __restrict__ b3)
{
    int rin0, rin1, rout;
    if (S == 0) { rin0 = 2 - it;   rin1 = 3 - it;   rout = 1 - it;   }
    else        { rin0 = 255 + it; rin1 = 256 + it; rout = 258 + it; }
    const int a0 = bmap(rin0), a1 = bmap(rin1), ao = bmap(rout);
    for (int j0 = tid; j0 < 258; j0 += 512) {
        int j = j0 + 1;
        float v[6];
        v[0] = rowS[a0][j - 1]; v[1] = rowS[a0][j]; v[2] = rowS[a0][j + 1];
        v[3] = rowS[a1][j - 1]; v[4] = rowS[a1][j]; v[5] = rowS[a1][j + 1];
        float o = mlp6<S>(v, w1, b1, w2, b2, w3, b3);
        rowS[ao][j] = o;
        if (j < 4 || j >= 255) colS[bmap(j)][rout] = o;  // keep col views consistent
    }
}

template <int S>
__device__ __forceinline__ void vstage(int it, int tid,
                                       float (*rowS)[260], float (*colS)[260],
                                       const float* __restrict__ w1, const float* __restrict__ b1,
                                       const float* __restrict__ w2, const float* __restrict__ b2,
                                       const float* __restrict__ w3, const float* __restrict__ b3)
{
    int cin0, cin1, cout;
    if (S == 2) { cin0 = 2 - it;   cin1 = 3 - it;   cout = 1 - it;   }
    else        { cin0 = 255 + it; cin1 = 256 + it; cout = 258 + it; }
    const int a0 = bmap(cin0), a1 = bmap(cin1), ao = bmap(cout);
    for (int r0 = tid; r0 < 258; r0 += 512) {
        int r = r0 + 1;
        float v[6];
        v[0] = colS[a0][r - 1]; v[1] = colS[a0][r]; v[2] = colS[a0][r + 1];
        v[3] = colS[a1][r - 1]; v[4] = colS[a1][r]; v[5] = colS[a1][r + 1];
        float o = mlp6<S>(v, w1, b1, w2, b2, w3, b3);
        colS[ao][r] = o;
        if (r < 4 || r >= 255) rowS[bmap(r)][cout] = o;  // keep row views consistent
    }
}

__global__ __launch_bounds__(512) void padding_kernel(
    const float* __restrict__ x,
    const float* __restrict__ w1, const float* __restrict__ b1,
    const float* __restrict__ w2, const float* __restrict__ b2,
    const float* __restrict__ w3, const float* __restrict__ b3,
    float* __restrict__ out)
{
    const int tid = threadIdx.x;
    const int bc  = blockIdx.x;                     // b*128 + c
    const float* xs = x + (size_t)bc * 65536;
    float*       os = out + (size_t)bc * 67600;

    // tracked xp rows/cols {0,1,2,3,255,256,257,258,259} -> 0..8
    __shared__ float rowS[9][260];
    __shared__ float colS[9][260];

    // 1) zero-init LDS (no barrier needed yet; sync at step 3 covers it)
    for (int idx = tid; idx < 9 * 260; idx += 512) {
        (&rowS[0][0])[idx] = 0.f;
        (&colS[0][0])[idx] = 0.f;
    }

    // 2) interior stream: 65 aligned float4 per row, junk at frame cols
    for (int idx = tid; idx < 256 * 65; idx += 512) {
        int r = idx / 65;
        int k = idx - r * 65;
        float*       orow = os + (size_t)(r + 2) * 260;
        const float* xrow = xs + (size_t)r * 256;
        f32x4 val;
        if (k == 0) {            // xp cols 0..3: {junk,junk,x0,x1}
            f32x2 a = *(const f32x2*)(xrow);
            val = (f32x4){a.x, a.y, a.x, a.y};
        } else if (k == 64) {    // xp cols 256..259: {x254,x255,junk,junk}
            f32x2 c = *(const f32x2*)(xrow + 254);
            val = (f32x4){c.x, c.y, c.x, c.y};
        } else {                 // xp cols 4k..4k+3 = x[4k-2..4k+1]
            f32x2 a = *(const f32x2*)(xrow + 4 * k - 2);
            f32x2 c = *(const f32x2*)(xrow + 4 * k);
            val = (f32x4){a.x, a.y, c.x, c.y};
        }
        *(f32x4*)(orow + 4 * k) = val;
    }

    // 3) barrier: drains vmcnt -> junk stores committed to this XCD's L2
    //    before any patch store below; also orders LDS zero vs gather.
    __syncthreads();

    // 4) gather border inputs (staggered across blocks, warm L2/L3)
    for (int idx = tid; idx < 5 * 256; idx += 512) {
        int which = idx >> 8, t = idx & 255;
        int xr = which < 2 ? which : 251 + which;   // x rows 0,1,253,254,255
        rowS[2 + which][2 + t] = xs[xr * 256 + t];
    }
    for (int idx = tid; idx < 5 * 256; idx += 512) {
        int which = idx >> 8, t = idx & 255;
        int xr = which < 2 ? which : 251 + which;
        colS[2 + which][2 + t] = xs[t * 256 + xr];  // strided, staggered
    }
    __syncthreads();

    // 5) border program — pure LDS+VALU
    for (int it = 0; it < 2; ++it) {
        hstage<0>(it, tid, rowS, colS, w1, b1, w2, b2, w3, b3);
        hstage<1>(it, tid, rowS, colS, w1, b1, w2, b2, w3, b3);
        __syncthreads();
        vstage<2>(it, tid, rowS, colS, w1, b1, w2, b2, w3, b3);
        vstage<3>(it, tid, rowS, colS, w1, b1, w2, b2, w3, b3);
        __syncthreads();
    }

    // 6) patch frame. rows 0,1,258,259 full width (corners = 0 as in ref)
    for (int idx = tid; idx < 4 * 260; idx += 512) {
        int w = idx / 260, cc = idx % 260;
        int rr = w < 2 ? w : 256 + w;               // 0,1,258,259
        os[(size_t)rr * 260 + cc] = rowS[bmap(rr)][cc];
    }
    // col strips: cols 0,1 and 258,259 for rows 2..257 (overwrite stream junk)
    for (int idx = tid; idx < 2 * 256; idx += 512) {
        int w = idx >> 8;                           // 0 = left, 1 = right
        int r = (idx & 255) + 2;
        float* orow = os + (size_t)r * 260;
        if (w == 0) *(f32x2*)(orow)       = (f32x2){colS[0][r], colS[1][r]};
        else        *(f32x2*)(orow + 258) = (f32x2){colS[7][r], colS[8][r]};
    }
}

extern "C" void kernel_launch(void* const* d_in, const int* in_sizes, int n_in,
                              void* d_out, int out_size, void* d_ws, size_t ws_size,
                              hipStream_t stream)
{
    const float* x  = (const float*)d_in[0];
    const float* w1 = (const float*)d_in[1];
    const float* b1 = (const float*)d_in[2];
    const float* w2 = (const float*)d_in[3];
    const float* b2 = (const float*)d_in[4];
    const float* w3 = (const float*)d_in[5];
    const float* b3 = (const float*)d_in[6];
    float* out = (float*)d_out;

    padding_kernel<<<1024, 512, 0, stream>>>(x, w1, b1, w2, b2, w3, b3, out);
}